// Round 5
// baseline (198.930 us; speedup 1.0000x reference)
//
#include <hip/hip_runtime.h>

#define BB 8
#define TT 2048
#define CC 1024
#define HH 64
#define MM (BB * TT)   // 16384 rows

typedef _Float16 half8 __attribute__((ext_vector_type(8)));
typedef _Float16 half4 __attribute__((ext_vector_type(4)));
typedef float floatx4 __attribute__((ext_vector_type(4)));

// 16-lane all-reduce max via DPP row-rotate butterfly (VALU pipe, no LDS).
template <int CTRL>
__device__ __forceinline__ float dpp_max_step(float x)
{
    union { float f; int i; } u, v;
    u.f = x;
    v.i = __builtin_amdgcn_update_dpp(u.i, u.i, CTRL, 0xf, 0xf, false);
    return fmaxf(x, v.f);
}
__device__ __forceinline__ float rowmax16(float x)
{
    x = dpp_max_step<0x128>(x);   // ROW_ROR:8
    x = dpp_max_step<0x124>(x);   // ROW_ROR:4
    x = dpp_max_step<0x122>(x);   // ROW_ROR:2
    x = dpp_max_step<0x121>(x);   // ROW_ROR:1
    return x;
}

// ---------------------------------------------------------------------------
// Kernel 0: pack W -> fp16 W16[192][1024]; rows 0..63 = Wq * 8 (sqrt(H) fold),
// 64..127 = Wk, 128..191 = Wv.
// ---------------------------------------------------------------------------
__global__ __launch_bounds__(256)
void w_convert(const float* __restrict__ Wk, const float* __restrict__ Wq,
               const float* __restrict__ Wv, _Float16* __restrict__ W16)
{
    const int e = (blockIdx.x * 256 + threadIdx.x) * 8;
    const int row = e >> 10;            // 0..191
    const int c   = e & 1023;
    const int which = row >> 6;
    const float* __restrict__ src = (which == 0) ? Wq : ((which == 1) ? Wk : Wv);
    const float scale = (which == 0) ? 8.0f : 1.0f;
    const int srow = row & 63;
    const float4 a = *reinterpret_cast<const float4*>(&src[srow * 1024 + c]);
    const float4 b = *reinterpret_cast<const float4*>(&src[srow * 1024 + c + 4]);
    const half8 o = { (_Float16)(a.x * scale), (_Float16)(a.y * scale),
                      (_Float16)(a.z * scale), (_Float16)(a.w * scale),
                      (_Float16)(b.x * scale), (_Float16)(b.y * scale),
                      (_Float16)(b.z * scale), (_Float16)(b.w * scale) };
    *reinterpret_cast<half8*>(&W16[e]) = o;
}

// ---------------------------------------------------------------------------
// Kernel 1: QKV projection. Wave = 16 rows x 96 cols (6 n-frags), K=1024.
// 2048 waves = 512 blocks x 256 thr -> 2 waves/SIMD (latency hiding).
// x staged via per-wave-private LDS (coalesced 256B/row global loads, no
// barriers); W16 read direct (L2-resident, 384 KB). ~70 VGPR, no pipeline
// register blowup. V written pre-transposed vt16[b][h][t].
// ---------------------------------------------------------------------------
__global__ __launch_bounds__(256, 2)
void qkv2(const float* __restrict__ x, const _Float16* __restrict__ W16,
          _Float16* __restrict__ q16, _Float16* __restrict__ k16,
          _Float16* __restrict__ vt16)
{
    __shared__ _Float16 Xs[4 * 16 * 68];

    const int tid  = threadIdx.x;
    const int lane = tid & 63;
    const int wv   = tid >> 6;
    const int gw   = blockIdx.x * 4 + wv;   // 0..2047
    const int mtile = gw >> 1;              // 0..1023
    const int nh    = gw & 1;               // n-half: cols nh*96 .. +96
    const int fm = lane & 15;
    const int fq = lane >> 4;
    const int fk = fq * 8;
    const int fr = fq * 4;
    const int m_base = mtile * 16;

    _Float16* __restrict__ Xw = &Xs[wv * 16 * 68];
    const _Float16* __restrict__ wb = &W16[(size_t)(nh * 96 + fm) * CC + fk];

    floatx4 acc[6];
    #pragma unroll
    for (int n = 0; n < 6; ++n)
        #pragma unroll
        for (int r = 0; r < 4; ++r) acc[n][r] = 0.0f;

    for (int k0 = 0; k0 < CC; k0 += 64) {
        // ---- stage x chunk (16 rows x 64 cols) into private LDS ----
        // load: instr i covers rows i*4+fq, 256 B contiguous per row
        #pragma unroll
        for (int i = 0; i < 4; ++i) {
            const float4 xv = *reinterpret_cast<const float4*>(
                &x[(size_t)(m_base + i * 4 + fq) * CC + k0 + fm * 4]);
            const half4 h = { (_Float16)xv.x, (_Float16)xv.y,
                              (_Float16)xv.z, (_Float16)xv.w };
            *reinterpret_cast<half4*>(&Xw[(i * 4 + fq) * 68 + fm * 4]) = h;
        }
        // A-frags (wave-internal lgkmcnt ordering, no barrier)
        const half8 af0 = *reinterpret_cast<const half8*>(&Xw[fm * 68 + fk]);
        const half8 af1 = *reinterpret_cast<const half8*>(&Xw[fm * 68 + 32 + fk]);

        #pragma unroll
        for (int n = 0; n < 6; ++n) {
            const _Float16* wp = wb + (size_t)n * 16 * CC + k0;
            const half8 b0 = *reinterpret_cast<const half8*>(wp);
            const half8 b1 = *reinterpret_cast<const half8*>(wp + 32);
            acc[n] = __builtin_amdgcn_mfma_f32_16x16x32_f16(af0, b0, acc[n], 0, 0, 0);
            acc[n] = __builtin_amdgcn_mfma_f32_16x16x32_f16(af1, b1, acc[n], 0, 0, 0);
        }
    }

    // epilogue: col = nh*96 + n*16 + fm; <64 q, <128 k, else v transposed
    const int b  = m_base >> 11;
    const int t0 = m_base & 2047;
    #pragma unroll
    for (int n = 0; n < 6; ++n) {
        const int col = nh * 96 + n * 16 + fm;
        if (col < 128) {
            _Float16* __restrict__ dst = (col < 64) ? q16 : k16;
            const int h = col & 63;
            #pragma unroll
            for (int r = 0; r < 4; ++r)
                dst[(size_t)(m_base + fr + r) * HH + h] = (_Float16)acc[n][r];
        } else {
            const int h = col - 128;
            const half4 pk = { (_Float16)acc[n][0], (_Float16)acc[n][1],
                               (_Float16)acc[n][2], (_Float16)acc[n][3] };
            *reinterpret_cast<half4*>(
                &vt16[((size_t)b * HH + h) * TT + t0 + fr]) = pk;
        }
    }
}

// ---------------------------------------------------------------------------
// Kernel 2: barrier-free fused causal attention. One wave owns a 16-row
// q-tile: K/V B-frags loaded direct from L2-hot global (no shared LDS tiles,
// NO __syncthreads). P round-trips through per-wave-private LDS. Softmax:
// DPP row-max (VALU) + ones-MFMA row-sum. 1024 waves = 256 blocks x 256 thr.
// ---------------------------------------------------------------------------
__global__ __launch_bounds__(256, 1)
void attn(const _Float16* __restrict__ q16, const _Float16* __restrict__ k16,
          const _Float16* __restrict__ vt16, float* __restrict__ out)
{
    __shared__ _Float16 Ps[4 * 16 * 68];

    const int tid  = threadIdx.x;
    const int lane = tid & 63;
    const int wv   = tid >> 6;
    const int gw   = blockIdx.x * 4 + wv;   // 0..1023
    const int b    = gw >> 7;               // batch
    const int it   = gw & 127;              // 16-row q tile
    const int fm = lane & 15;
    const int fq = lane >> 4;
    const int fk = fq * 8;
    const int fr = fq * 4;

    const _Float16* __restrict__ qb  = q16  + (size_t)b * TT * HH;
    const _Float16* __restrict__ kb  = k16  + (size_t)b * TT * HH;
    const _Float16* __restrict__ vtb = vt16 + (size_t)b * HH * TT;
    _Float16* __restrict__ Pw = &Ps[wv * 16 * 68];

    const int qrow = it * 16 + fm;
    const half8 qf0 = *reinterpret_cast<const half8*>(&qb[(size_t)qrow * HH + fk]);
    const half8 qf1 = *reinterpret_cast<const half8*>(&qb[(size_t)qrow * HH + 32 + fk]);

    floatx4 O[4], lacc;
    float m_r[4];
    #pragma unroll
    for (int r = 0; r < 4; ++r) {
        m_r[r] = -3.0e38f;
        lacc[r] = 0.0f;
        #pragma unroll
        for (int ht = 0; ht < 4; ++ht) O[ht][r] = 0.0f;
    }
    const half8 ones = { (_Float16)1.f, (_Float16)1.f, (_Float16)1.f, (_Float16)1.f,
                         (_Float16)1.f, (_Float16)1.f, (_Float16)1.f, (_Float16)1.f };

    const int Ji = (it >> 2) + 1;

    for (int j = 0; j < Ji; ++j) {
        const _Float16* __restrict__ kjb = kb + (size_t)j * 64 * HH;
        const _Float16* __restrict__ vjb = vtb + j * 64;

        // ---- S = Q K^T : 8 MFMAs, K B-frags direct from global (L2-hot) ----
        floatx4 sa[4];
        #pragma unroll
        for (int nt = 0; nt < 4; ++nt) {
            #pragma unroll
            for (int r = 0; r < 4; ++r) sa[nt][r] = 0.0f;
            const _Float16* kp = kjb + (size_t)(nt * 16 + fm) * HH;
            const half8 b0 = *reinterpret_cast<const half8*>(kp + fk);
            const half8 b1 = *reinterpret_cast<const half8*>(kp + 32 + fk);
            sa[nt] = __builtin_amdgcn_mfma_f32_16x16x32_f16(qf0, b0, sa[nt], 0, 0, 0);
            sa[nt] = __builtin_amdgcn_mfma_f32_16x16x32_f16(qf1, b1, sa[nt], 0, 0, 0);
        }

        // ---- causal mask (only diagonal j-tile) ----
        if (j == Ji - 1) {
            const int rbase = it * 16 + fr;
            #pragma unroll
            for (int nt = 0; nt < 4; ++nt) {
                const int col = j * 64 + nt * 16 + fm;
                #pragma unroll
                for (int r = 0; r < 4; ++r)
                    if (col > rbase + r) sa[nt][r] = -3.0e38f;
            }
        }

        // ---- online softmax: DPP max; row-sum via ones-MFMA ----
        #pragma unroll
        for (int r = 0; r < 4; ++r) {
            float mx = fmaxf(fmaxf(sa[0][r], sa[1][r]), fmaxf(sa[2][r], sa[3][r]));
            mx = rowmax16(mx);
            const float mn = fmaxf(m_r[r], mx);
            const float alpha = __expf(m_r[r] - mn);
            m_r[r] = mn;
            _Float16* pp = &Pw[(fr + r) * 68 + fm];
            pp[0]  = (_Float16)__expf(sa[0][r] - mn);
            pp[16] = (_Float16)__expf(sa[1][r] - mn);
            pp[32] = (_Float16)__expf(sa[2][r] - mn);
            pp[48] = (_Float16)__expf(sa[3][r] - mn);
            lacc[r] *= alpha;
            O[0][r] *= alpha; O[1][r] *= alpha; O[2][r] *= alpha; O[3][r] *= alpha;
        }
        // wave-private LDS: lgkmcnt ordering only, no barrier

        // ---- O += P V, l += P 1 : 10 MFMAs; V B-frags direct from global ----
        #pragma unroll
        for (int ch = 0; ch < 2; ++ch) {
            const half8 pa = *reinterpret_cast<const half8*>(
                &Pw[fm * 68 + ch * 32 + fk]);
            lacc = __builtin_amdgcn_mfma_f32_16x16x32_f16(pa, ones, lacc, 0, 0, 0);
            #pragma unroll
            for (int ht = 0; ht < 4; ++ht) {
                const half8 vb = *reinterpret_cast<const half8*>(
                    &vjb[(size_t)(ht * 16 + fm) * TT + ch * 32 + fk]);
                O[ht] = __builtin_amdgcn_mfma_f32_16x16x32_f16(pa, vb, O[ht], 0, 0, 0);
            }
        }
    }

    // ---- epilogue: out = O / l ----
    #pragma unroll
    for (int r = 0; r < 4; ++r) {
        const float inv = 1.0f / lacc[r];
        const size_t rowoff = (size_t)(b * TT + it * 16 + fr + r) * HH;
        #pragma unroll
        for (int ht = 0; ht < 4; ++ht)
            out[rowoff + ht * 16 + fm] = O[ht][r] * inv;
    }
}

// ---------------------------------------------------------------------------
extern "C" void kernel_launch(void* const* d_in, const int* in_sizes, int n_in,
                              void* d_out, int out_size, void* d_ws, size_t ws_size,
                              hipStream_t stream)
{
    (void)in_sizes; (void)n_in; (void)out_size; (void)ws_size;

    const float* x  = (const float*)d_in[0];
    const float* Wk = (const float*)d_in[1];
    const float* Wq = (const float*)d_in[2];
    const float* Wv = (const float*)d_in[3];
    float* out = (float*)d_out;

    _Float16* q16  = (_Float16*)d_ws;                     // [MM][HH]
    _Float16* k16  = q16 + (size_t)MM * HH;               // [MM][HH]
    _Float16* vt16 = k16 + (size_t)MM * HH;               // [BB][HH][TT]
    _Float16* W16  = vt16 + (size_t)MM * HH;              // [192][1024]

    w_convert<<<dim3(96), dim3(256), 0, stream>>>(Wk, Wq, Wv, W16);
    qkv2<<<dim3(512), dim3(256), 0, stream>>>(x, W16, q16, k16, vt16);
    attn<<<dim3(256), dim3(256), 0, stream>>>(q16, k16, vt16, out);
}

// Round 6
// 187.789 us; speedup vs baseline: 1.0593x; 1.0593x over previous
//
#include <hip/hip_runtime.h>

#define BB 8
#define TT 2048
#define CC 1024
#define HH 64
#define MM (BB * TT)   // 16384 rows

typedef _Float16 half8 __attribute__((ext_vector_type(8)));
typedef _Float16 half4 __attribute__((ext_vector_type(4)));
typedef float floatx4 __attribute__((ext_vector_type(4)));

// 16-lane all-reduce max via DPP row-rotate butterfly (VALU pipe, no LDS).
template <int CTRL>
__device__ __forceinline__ float dpp_max_step(float x)
{
    union { float f; int i; } u, v;
    u.f = x;
    v.i = __builtin_amdgcn_update_dpp(u.i, u.i, CTRL, 0xf, 0xf, false);
    return fmaxf(x, v.f);
}
__device__ __forceinline__ float rowmax16(float x)
{
    x = dpp_max_step<0x128>(x);   // ROW_ROR:8
    x = dpp_max_step<0x124>(x);   // ROW_ROR:4
    x = dpp_max_step<0x122>(x);   // ROW_ROR:2
    x = dpp_max_step<0x121>(x);   // ROW_ROR:1
    return x;
}

// ---------------------------------------------------------------------------
// Kernel 0: pack W into fragment-major fp16 layout:
//   Wp[(c*192 + row)*32 + kk] = Wscaled[row][c*32 + kk],  c = K-chunk (32 k)
// rows 0..63 = Wq*8 (sqrt(H) fold), 64..127 = Wk, 128..191 = Wv.
// A 16x16x32 B-fragment (rows nt*16..+16, k fk..fk+8) is then CONTIGUOUS 1KB.
// ---------------------------------------------------------------------------
__global__ __launch_bounds__(256)
void w_pack(const float* __restrict__ Wk, const float* __restrict__ Wq,
            const float* __restrict__ Wv, _Float16* __restrict__ Wp)
{
    const int idx = (blockIdx.x * 256 + threadIdx.x) * 8;  // 0..196600
    const int c   = idx / 6144;          // 192*32 = 6144
    const int rm  = idx - c * 6144;
    const int row = rm >> 5;             // 0..191
    const int kk  = rm & 31;             // 0,8,16,24
    const int which = row >> 6;
    const float* __restrict__ src = (which == 0) ? Wq : ((which == 1) ? Wk : Wv);
    const float scale = (which == 0) ? 8.0f : 1.0f;
    const int srow = row & 63;
    const int k = c * 32 + kk;
    const float4 a = *reinterpret_cast<const float4*>(&src[srow * 1024 + k]);
    const float4 b = *reinterpret_cast<const float4*>(&src[srow * 1024 + k + 4]);
    const half8 o = { (_Float16)(a.x * scale), (_Float16)(a.y * scale),
                      (_Float16)(a.z * scale), (_Float16)(a.w * scale),
                      (_Float16)(b.x * scale), (_Float16)(b.y * scale),
                      (_Float16)(b.z * scale), (_Float16)(b.w * scale) };
    *reinterpret_cast<half8*>(&Wp[idx]) = o;
}

// ---------------------------------------------------------------------------
// Kernel 1: QKV projection. 1024 blocks x 64 threads = 1 wave/block, NO
// barriers, 4 independent blocks/CU. Wave = 16 rows x 192 cols (12 n-frags).
// B-frags: contiguous 1KB loads from packed Wp (L2-resident).
// A-frags: direct x loads (16 rows x 64B fully-used lines) + inline cvt.
// V written pre-transposed vt16[b][h][t].
// ---------------------------------------------------------------------------
__global__ __launch_bounds__(64, 2)
void qkv5(const float* __restrict__ x, const _Float16* __restrict__ Wp,
          _Float16* __restrict__ q16, _Float16* __restrict__ k16,
          _Float16* __restrict__ vt16)
{
    const int lane = threadIdx.x;
    const int m_base = blockIdx.x * 16;
    const int fm = lane & 15;
    const int fq = lane >> 4;
    const int fk = fq * 8;
    const int fr = fq * 4;

    const float* __restrict__ xrow = &x[(size_t)(m_base + fm) * CC + fk];

    floatx4 acc[12];
    #pragma unroll
    for (int n = 0; n < 12; ++n)
        #pragma unroll
        for (int r = 0; r < 4; ++r) acc[n][r] = 0.0f;

    #pragma unroll 2
    for (int c = 0; c < 32; ++c) {
        const float4 xa = *reinterpret_cast<const float4*>(xrow + c * 32);
        const float4 xb = *reinterpret_cast<const float4*>(xrow + c * 32 + 4);
        const half8 af = { (_Float16)xa.x, (_Float16)xa.y, (_Float16)xa.z, (_Float16)xa.w,
                           (_Float16)xb.x, (_Float16)xb.y, (_Float16)xb.z, (_Float16)xb.w };
        const _Float16* __restrict__ wc = &Wp[c * 6144 + fm * 32 + fk];
        #pragma unroll
        for (int n = 0; n < 12; ++n) {
            const half8 bf = *reinterpret_cast<const half8*>(wc + n * 512);
            acc[n] = __builtin_amdgcn_mfma_f32_16x16x32_f16(af, bf, acc[n], 0, 0, 0);
        }
    }

    // epilogue: col = n*16 + fm; <64 q, <128 k, else v transposed
    const int b  = m_base >> 11;
    const int t0 = m_base & 2047;
    #pragma unroll
    for (int n = 0; n < 12; ++n) {
        const int col = n * 16 + fm;
        if (col < 128) {
            _Float16* __restrict__ dst = (col < 64) ? q16 : k16;
            const int h = col & 63;
            #pragma unroll
            for (int r = 0; r < 4; ++r)
                dst[(size_t)(m_base + fr + r) * HH + h] = (_Float16)acc[n][r];
        } else {
            const int h = col - 128;
            const half4 pk = { (_Float16)acc[n][0], (_Float16)acc[n][1],
                               (_Float16)acc[n][2], (_Float16)acc[n][3] };
            *reinterpret_cast<half4*>(
                &vt16[((size_t)b * HH + h) * TT + t0 + fr]) = pk;
        }
    }
}

// ---------------------------------------------------------------------------
// Kernel 2: split-K fused causal attention. 768 blocks = 32 q-tiles(64 rows)
// x 8 batches x 3 key-segments, longest-first. Block 256 thr = 4 waves
// sharing LDS-staged K/V tiles (coalesced global loads, ds_read frags only).
// DPP row-max + ones-MFMA row-sum. Partials: seg0 -> d_out (fp32) + ml;
// segs 1,2 -> fp16 Op + ml. 3 blocks/CU so barrier drains overlap.
// ---------------------------------------------------------------------------
__global__ __launch_bounds__(256, 3)
void attn5(const _Float16* __restrict__ q16, const _Float16* __restrict__ k16,
           const _Float16* __restrict__ vt16, float* __restrict__ out,
           _Float16* __restrict__ Op, float* __restrict__ ml)
{
    __shared__ _Float16 Ks[64 * 68];
    __shared__ _Float16 Vts[64 * 68];
    __shared__ _Float16 Ps[4 * 16 * 68];

    const int bid = blockIdx.x;           // 0..767
    const int it  = 31 - (bid / 24);      // longest tiles dispatched first
    const int sub = bid - (31 - it) * 24;
    const int b   = sub & 7;
    const int s   = sub >> 3;             // segment 0..2

    const int tid  = threadIdx.x;
    const int lane = tid & 63;
    const int wv   = tid >> 6;
    const int fm   = lane & 15;
    const int fq   = lane >> 4;
    const int fk   = fq * 8;
    const int fr   = fq * 4;

    const int Ji   = it + 1;
    const int qq   = Ji / 3, rem = Ji - qq * 3;
    const int cnt  = qq + (s < rem ? 1 : 0);
    const int start = s * qq + (s < rem ? s : rem);

    const _Float16* __restrict__ qb  = q16  + (size_t)b * TT * HH;
    const _Float16* __restrict__ kb  = k16  + (size_t)b * TT * HH;
    const _Float16* __restrict__ vtb = vt16 + (size_t)b * HH * TT;

    const int qrow = it * 64 + wv * 16 + fm;
    const half8 qf0 = *reinterpret_cast<const half8*>(&qb[(size_t)qrow * HH + fk]);
    const half8 qf1 = *reinterpret_cast<const half8*>(&qb[(size_t)qrow * HH + 32 + fk]);

    floatx4 O[4], lacc;
    float m_r[4];
    #pragma unroll
    for (int r = 0; r < 4; ++r) {
        m_r[r] = -3.0e38f;
        lacc[r] = 0.0f;
        #pragma unroll
        for (int ht = 0; ht < 4; ++ht) O[ht][r] = 0.0f;
    }
    const half8 ones = { (_Float16)1.f, (_Float16)1.f, (_Float16)1.f, (_Float16)1.f,
                         (_Float16)1.f, (_Float16)1.f, (_Float16)1.f, (_Float16)1.f };

    const int sr = tid >> 2;           // 0..63
    const int sc = (tid & 3) * 16;     // 0,16,32,48

    for (int js = 0; js < cnt; ++js) {
        const int jj = start + js;
        const _Float16* __restrict__ ksrc = &kb[(size_t)(jj * 64 + sr) * HH + sc];
        const _Float16* __restrict__ vsrc = &vtb[(size_t)sr * TT + jj * 64 + sc];

        __syncthreads();   // prior iteration's LDS reads complete
        *reinterpret_cast<half8*>(&Ks[sr * 68 + sc])      = *reinterpret_cast<const half8*>(ksrc);
        *reinterpret_cast<half8*>(&Ks[sr * 68 + sc + 8])  = *reinterpret_cast<const half8*>(ksrc + 8);
        *reinterpret_cast<half8*>(&Vts[sr * 68 + sc])     = *reinterpret_cast<const half8*>(vsrc);
        *reinterpret_cast<half8*>(&Vts[sr * 68 + sc + 8]) = *reinterpret_cast<const half8*>(vsrc + 8);
        __syncthreads();

        // ---- S = Q K^T : 8 MFMAs, B-frags from LDS ----
        floatx4 sa[4];
        #pragma unroll
        for (int nt = 0; nt < 4; ++nt) {
            #pragma unroll
            for (int r = 0; r < 4; ++r) sa[nt][r] = 0.0f;
            const _Float16* kp = &Ks[(nt * 16 + fm) * 68];
            const half8 b0 = *reinterpret_cast<const half8*>(kp + fk);
            const half8 b1 = *reinterpret_cast<const half8*>(kp + 32 + fk);
            sa[nt] = __builtin_amdgcn_mfma_f32_16x16x32_f16(qf0, b0, sa[nt], 0, 0, 0);
            sa[nt] = __builtin_amdgcn_mfma_f32_16x16x32_f16(qf1, b1, sa[nt], 0, 0, 0);
        }

        // ---- causal mask (only the global diagonal tile jj == it) ----
        if (jj == it) {
            const int rbase = it * 64 + wv * 16 + fr;
            #pragma unroll
            for (int nt = 0; nt < 4; ++nt) {
                const int col = jj * 64 + nt * 16 + fm;
                #pragma unroll
                for (int r = 0; r < 4; ++r)
                    if (col > rbase + r) sa[nt][r] = -3.0e38f;
            }
        }

        // ---- online softmax: DPP row-max; row-sum via ones-MFMA ----
        #pragma unroll
        for (int r = 0; r < 4; ++r) {
            float mx = fmaxf(fmaxf(sa[0][r], sa[1][r]), fmaxf(sa[2][r], sa[3][r]));
            mx = rowmax16(mx);
            const float mn = fmaxf(m_r[r], mx);
            const float alpha = __expf(m_r[r] - mn);
            m_r[r] = mn;
            _Float16* pp = &Ps[wv * 1088 + (fr + r) * 68 + fm];
            pp[0]  = (_Float16)__expf(sa[0][r] - mn);
            pp[16] = (_Float16)__expf(sa[1][r] - mn);
            pp[32] = (_Float16)__expf(sa[2][r] - mn);
            pp[48] = (_Float16)__expf(sa[3][r] - mn);
            lacc[r] *= alpha;
            O[0][r] *= alpha; O[1][r] *= alpha; O[2][r] *= alpha; O[3][r] *= alpha;
        }
        // Ps is per-wave-private: lgkmcnt ordering suffices, no barrier

        // ---- O += P V, l += P 1 : 10 MFMAs ----
        #pragma unroll
        for (int ch = 0; ch < 2; ++ch) {
            const half8 pa = *reinterpret_cast<const half8*>(
                &Ps[wv * 1088 + fm * 68 + ch * 32 + fk]);
            lacc = __builtin_amdgcn_mfma_f32_16x16x32_f16(pa, ones, lacc, 0, 0, 0);
            #pragma unroll
            for (int ht = 0; ht < 4; ++ht) {
                const half8 vb = *reinterpret_cast<const half8*>(
                    &Vts[(ht * 16 + fm) * 68 + ch * 32 + fk]);
                O[ht] = __builtin_amdgcn_mfma_f32_16x16x32_f16(pa, vb, O[ht], 0, 0, 0);
            }
        }
    }

    // ---- epilogue: write segment partial (unnormalized O, m, l) ----
    #pragma unroll
    for (int r = 0; r < 4; ++r) {
        const int grow = b * TT + it * 64 + wv * 16 + fr + r;
        if (s == 0) {
            #pragma unroll
            for (int ht = 0; ht < 4; ++ht)
                out[(size_t)grow * HH + ht * 16 + fm] = O[ht][r];
        } else {
            #pragma unroll
            for (int ht = 0; ht < 4; ++ht)
                Op[((size_t)(s - 1) * MM + grow) * HH + ht * 16 + fm] = (_Float16)O[ht][r];
        }
        if (fm == 0) {
            ml[((size_t)s * MM + grow) * 2 + 0] = m_r[r];
            ml[((size_t)s * MM + grow) * 2 + 1] = lacc[r];
        }
    }
}

// ---------------------------------------------------------------------------
// Kernel 3: flash-decode combine of the 3 segment partials.
// 256 blocks x 256 thr; thread = (row, 16-col strip).
// ---------------------------------------------------------------------------
__global__ __launch_bounds__(256)
void combine(float* __restrict__ out, const _Float16* __restrict__ Op,
             const float* __restrict__ ml)
{
    const int tid  = threadIdx.x;
    const int grow = blockIdx.x * 64 + (tid >> 2);
    const int c0   = (tid & 3) * 16;

    const float m0 = ml[(size_t)grow * 2 + 0];
    const float l0 = ml[(size_t)grow * 2 + 1];
    const float m1 = ml[((size_t)MM + grow) * 2 + 0];
    const float l1 = ml[((size_t)MM + grow) * 2 + 1];
    const float m2 = ml[((size_t)2 * MM + grow) * 2 + 0];
    const float l2 = ml[((size_t)2 * MM + grow) * 2 + 1];

    const float M  = fmaxf(m0, fmaxf(m1, m2));
    const float w0 = __expf(m0 - M);
    const float w1 = __expf(m1 - M);
    const float w2 = __expf(m2 - M);
    const float inv = 1.0f / (w0 * l0 + w1 * l1 + w2 * l2);

    #pragma unroll
    for (int i = 0; i < 16; i += 4) {
        float4 o0 = *reinterpret_cast<float4*>(&out[(size_t)grow * HH + c0 + i]);
        const half4 h1 = *reinterpret_cast<const half4*>(&Op[(size_t)grow * HH + c0 + i]);
        const half4 h2 = *reinterpret_cast<const half4*>(&Op[(size_t)MM * HH + (size_t)grow * HH + c0 + i]);
        o0.x = (w0 * o0.x + w1 * (float)h1[0] + w2 * (float)h2[0]) * inv;
        o0.y = (w0 * o0.y + w1 * (float)h1[1] + w2 * (float)h2[1]) * inv;
        o0.z = (w0 * o0.z + w1 * (float)h1[2] + w2 * (float)h2[2]) * inv;
        o0.w = (w0 * o0.w + w1 * (float)h1[3] + w2 * (float)h2[3]) * inv;
        *reinterpret_cast<float4*>(&out[(size_t)grow * HH + c0 + i]) = o0;
    }
}

// ---------------------------------------------------------------------------
extern "C" void kernel_launch(void* const* d_in, const int* in_sizes, int n_in,
                              void* d_out, int out_size, void* d_ws, size_t ws_size,
                              hipStream_t stream)
{
    (void)in_sizes; (void)n_in; (void)out_size; (void)ws_size;

    const float* x  = (const float*)d_in[0];
    const float* Wk = (const float*)d_in[1];
    const float* Wq = (const float*)d_in[2];
    const float* Wv = (const float*)d_in[3];
    float* out = (float*)d_out;

    _Float16* base = (_Float16*)d_ws;
    _Float16* q16  = base;                                 // 1,048,576 halves
    _Float16* k16  = base + (size_t)MM * HH;               // 1,048,576
    _Float16* vt16 = base + (size_t)2 * MM * HH;           // 1,048,576
    _Float16* Wp   = base + (size_t)3 * MM * HH;           // 196,608
    _Float16* Op   = Wp + 192 * 1024;                      // 2 * MM * HH halves
    float*    ml   = (float*)(Op + (size_t)2 * MM * HH);   // 3 * MM * 2 floats
    // total ws: ~10.9 MB

    w_pack<<<dim3(96), dim3(256), 0, stream>>>(Wk, Wq, Wv, Wp);
    qkv5<<<dim3(1024), dim3(64), 0, stream>>>(x, Wp, q16, k16, vt16);
    attn5<<<dim3(768), dim3(256), 0, stream>>>(q16, k16, vt16, out, Op, ml);
    combine<<<dim3(256), dim3(256), 0, stream>>>(out, Op, ml);
}

// Round 7
// 151.017 us; speedup vs baseline: 1.3173x; 1.2435x over previous
//
#include <hip/hip_runtime.h>

#define BB 8
#define TT 2048
#define CC 1024
#define HH 64
#define MM (BB * TT)   // 16384 rows

typedef _Float16 half8 __attribute__((ext_vector_type(8)));
typedef _Float16 half4 __attribute__((ext_vector_type(4)));
typedef float floatx4 __attribute__((ext_vector_type(4)));

// 16-lane all-reduce max via DPP row-rotate butterfly (VALU pipe, no LDS).
template <int CTRL>
__device__ __forceinline__ float dpp_max_step(float x)
{
    union { float f; int i; } u, v;
    u.f = x;
    v.i = __builtin_amdgcn_update_dpp(u.i, u.i, CTRL, 0xf, 0xf, false);
    return fmaxf(x, v.f);
}
__device__ __forceinline__ float rowmax16(float x)
{
    x = dpp_max_step<0x128>(x);   // ROW_ROR:8
    x = dpp_max_step<0x124>(x);   // ROW_ROR:4
    x = dpp_max_step<0x122>(x);   // ROW_ROR:2
    x = dpp_max_step<0x121>(x);   // ROW_ROR:1
    return x;
}

// ---------------------------------------------------------------------------
// Kernel 0: pack W into chunk-major fp16 layout:
//   Wp[(c*192 + row)*32 + kk] = Wscaled[row][c*32 + kk]   (c = K-chunk of 32)
// rows 0..63 = Wq*8 (sqrt(H) fold), 64..127 = Wk, 128..191 = Wv.
// A 16x16x32 B-fragment (16 rows x k32) is contiguous 1 KB.
// ---------------------------------------------------------------------------
__global__ __launch_bounds__(256)
void w_pack(const float* __restrict__ Wk, const float* __restrict__ Wq,
            const float* __restrict__ Wv, _Float16* __restrict__ Wp)
{
    const int idx = (blockIdx.x * 256 + threadIdx.x) * 8;  // 0..196600
    const int c   = idx / 6144;          // 192*32 = 6144
    const int rm  = idx - c * 6144;
    const int row = rm >> 5;             // 0..191
    const int kk  = rm & 31;             // 0,8,16,24
    const int which = row >> 6;
    const float* __restrict__ src = (which == 0) ? Wq : ((which == 1) ? Wk : Wv);
    const float scale = (which == 0) ? 8.0f : 1.0f;
    const int srow = row & 63;
    const int k = c * 32 + kk;
    const float4 a = *reinterpret_cast<const float4*>(&src[srow * 1024 + k]);
    const float4 b = *reinterpret_cast<const float4*>(&src[srow * 1024 + k + 4]);
    const half8 o = { (_Float16)(a.x * scale), (_Float16)(a.y * scale),
                      (_Float16)(a.z * scale), (_Float16)(a.w * scale),
                      (_Float16)(b.x * scale), (_Float16)(b.y * scale),
                      (_Float16)(b.z * scale), (_Float16)(b.w * scale) };
    *reinterpret_cast<half8*>(&Wp[idx]) = o;
}

// ---------------------------------------------------------------------------
// Kernel 1: QKV projection. Wave-tile 16 rows x 96 cols -> 2048 single-wave
// blocks (8 waves/CU, 2/SIMD). No LDS, no barriers. Explicit depth-1
// register double-buffer (~95 VGPR). x loads: 16 rows x 128 B full lines.
// W B-frags: contiguous 1 KB from packed Wp (L1/L2-hot).
// Outputs: q16 row-major; K and V in MFMA-fragment-packed layouts:
//   Kp[(kt*2 + hs)*512 + (key&15)*32 + (h&31)]   kt = global key/16, hs = h/32
//   Vp[(vt*4 + nt)*1024 + ks*512 + (h&15)*32 + (key&31)]
//        vt = global key/64, nt = h/16, ks = (key/32)&1
// ---------------------------------------------------------------------------
__global__ __launch_bounds__(64, 2)
void qkv7(const float* __restrict__ x, const _Float16* __restrict__ Wp,
          _Float16* __restrict__ q16, _Float16* __restrict__ Kp,
          _Float16* __restrict__ Vp)
{
    const int lane  = threadIdx.x;
    const int gw    = blockIdx.x;        // 0..2047
    const int mtile = gw >> 1;           // 0..1023
    const int nh    = gw & 1;            // n-half: cols nh*96 .. +96
    const int m_base = mtile * 16;
    const int fm = lane & 15;
    const int fq = lane >> 4;
    const int fk = fq * 8;
    const int fr = fq * 4;

    const float*    __restrict__ xrow = &x[(size_t)(m_base + fm) * CC + fk];
    const _Float16* __restrict__ wb   = &Wp[(nh * 96 + fm) * 32 + fk];

    floatx4 acc[6];
    #pragma unroll
    for (int n = 0; n < 6; ++n)
        #pragma unroll
        for (int r = 0; r < 4; ++r) acc[n][r] = 0.0f;

    float4 xa, xb, nxa, nxb;
    half8 wf[6], nwf[6];

    xa = *reinterpret_cast<const float4*>(xrow);
    xb = *reinterpret_cast<const float4*>(xrow + 4);
    #pragma unroll
    for (int n = 0; n < 6; ++n)
        wf[n] = *reinterpret_cast<const half8*>(wb + n * 512);

    #pragma unroll 2
    for (int c = 0; c < 32; ++c) {
        if (c < 31) {
            const float* xp = xrow + (c + 1) * 32;
            nxa = *reinterpret_cast<const float4*>(xp);
            nxb = *reinterpret_cast<const float4*>(xp + 4);
            const _Float16* wc = wb + (c + 1) * 6144;
            #pragma unroll
            for (int n = 0; n < 6; ++n)
                nwf[n] = *reinterpret_cast<const half8*>(wc + n * 512);
        }
        const half8 af = { (_Float16)xa.x, (_Float16)xa.y, (_Float16)xa.z, (_Float16)xa.w,
                           (_Float16)xb.x, (_Float16)xb.y, (_Float16)xb.z, (_Float16)xb.w };
        #pragma unroll
        for (int n = 0; n < 6; ++n)
            acc[n] = __builtin_amdgcn_mfma_f32_16x16x32_f16(af, wf[n], acc[n], 0, 0, 0);
        xa = nxa; xb = nxb;
        #pragma unroll
        for (int n = 0; n < 6; ++n) wf[n] = nwf[n];
    }

    // epilogue: col = nh*96 + n*16 + fm
    #pragma unroll
    for (int n = 0; n < 6; ++n) {
        const int col = nh * 96 + n * 16 + fm;
        if (col < 64) {                          // q: row-major
            #pragma unroll
            for (int r = 0; r < 4; ++r)
                q16[(size_t)(m_base + fr + r) * HH + col] = (_Float16)acc[n][r];
        } else if (col < 128) {                  // k: fragment-packed
            const int h = col - 64;
            _Float16* kp = &Kp[(size_t)(mtile * 2 + (h >> 5)) * 512 + (h & 31)];
            #pragma unroll
            for (int r = 0; r < 4; ++r)
                kp[(fr + r) * 32] = (_Float16)acc[n][r];
        } else {                                 // v: fragment-packed (transposed)
            const int h = col - 128;
            const half4 pk = { (_Float16)acc[n][0], (_Float16)acc[n][1],
                               (_Float16)acc[n][2], (_Float16)acc[n][3] };
            *reinterpret_cast<half4*>(
                &Vp[(size_t)((mtile >> 2) * 4 + (h >> 4)) * 1024 +
                    ((mtile >> 1) & 1) * 512 + fm * 32 + (mtile & 1) * 16 + fr]) = pk;
        }
    }
}

// ---------------------------------------------------------------------------
// Kernel 2: barrier-free split-K causal attention. 3072 single-wave blocks =
// 128 q-tiles(16 rows) x 8 batches x 3 key-segments, longest-first.
// 12 waves/CU (3/SIMD). K/V B-frags: contiguous 1 KB loads from Kp/Vp
// (L2-hot). P via 2.2 KB wave-private LDS (lgkmcnt ordering only).
// DPP row-max + ones-MFMA row-sum. Partials: seg0 -> out (fp32), segs 1,2 ->
// fp16 Op; (m,l) -> ml.
// ---------------------------------------------------------------------------
__global__ __launch_bounds__(64, 4)
void attn7(const _Float16* __restrict__ q16, const _Float16* __restrict__ Kp,
           const _Float16* __restrict__ Vp, float* __restrict__ out,
           _Float16* __restrict__ Op, float* __restrict__ ml)
{
    __shared__ _Float16 Ps[16 * 68];

    const int bid = blockIdx.x;           // 0..3071
    const int it  = 127 - bid / 24;       // longest q-tiles first
    const int sub = bid - (127 - it) * 24;
    const int b   = sub & 7;
    const int s   = sub >> 3;             // segment 0..2

    const int lane = threadIdx.x;
    const int fm = lane & 15;
    const int fq = lane >> 4;
    const int fk = fq * 8;
    const int fr = fq * 4;

    const int Ji = (it >> 2) + 1;
    const int qq = Ji / 3, rem = Ji - qq * 3;
    const int cnt   = qq + (s < rem ? 1 : 0);
    const int start = s * qq + (s < rem ? s : rem);

    const _Float16* __restrict__ kpb = Kp + (size_t)b * TT * HH;
    const _Float16* __restrict__ vpb = Vp + (size_t)b * TT * HH;

    const int qrow = (b * 128 + it) * 16 + fm;
    const half8 qf0 = *reinterpret_cast<const half8*>(&q16[(size_t)qrow * HH + fk]);
    const half8 qf1 = *reinterpret_cast<const half8*>(&q16[(size_t)qrow * HH + 32 + fk]);

    floatx4 O[4], lacc;
    float m_r[4];
    #pragma unroll
    for (int r = 0; r < 4; ++r) {
        m_r[r] = -3.0e38f;
        lacc[r] = 0.0f;
        #pragma unroll
        for (int ht = 0; ht < 4; ++ht) O[ht][r] = 0.0f;
    }
    const half8 ones = { (_Float16)1.f, (_Float16)1.f, (_Float16)1.f, (_Float16)1.f,
                         (_Float16)1.f, (_Float16)1.f, (_Float16)1.f, (_Float16)1.f };

    const int loff = fm * 32 + fk;        // per-lane offset inside a packed frag

    for (int js = 0; js < cnt; ++js) {
        const int jj = start + js;

        // ---- S = Q K^T : 8 MFMAs, B-frags = contiguous 1KB packed loads ----
        floatx4 sa[4];
        #pragma unroll
        for (int nt = 0; nt < 4; ++nt) {
            #pragma unroll
            for (int r = 0; r < 4; ++r) sa[nt][r] = 0.0f;
            const _Float16* kp = &kpb[(size_t)(jj * 4 + nt) * 1024];
            const half8 b0 = *reinterpret_cast<const half8*>(kp + loff);
            const half8 b1 = *reinterpret_cast<const half8*>(kp + 512 + loff);
            sa[nt] = __builtin_amdgcn_mfma_f32_16x16x32_f16(qf0, b0, sa[nt], 0, 0, 0);
            sa[nt] = __builtin_amdgcn_mfma_f32_16x16x32_f16(qf1, b1, sa[nt], 0, 0, 0);
        }

        // ---- causal mask (only the diagonal tile) ----
        if (jj == (it >> 2)) {
            const int rbase = it * 16 + fr;
            #pragma unroll
            for (int nt = 0; nt < 4; ++nt) {
                const int col = jj * 64 + nt * 16 + fm;
                #pragma unroll
                for (int r = 0; r < 4; ++r)
                    if (col > rbase + r) sa[nt][r] = -3.0e38f;
            }
        }

        // ---- online softmax: DPP row-max; row-sum via ones-MFMA ----
        #pragma unroll
        for (int r = 0; r < 4; ++r) {
            float mx = fmaxf(fmaxf(sa[0][r], sa[1][r]), fmaxf(sa[2][r], sa[3][r]));
            mx = rowmax16(mx);
            const float mn = fmaxf(m_r[r], mx);
            const float alpha = __expf(m_r[r] - mn);
            m_r[r] = mn;
            _Float16* pp = &Ps[(fr + r) * 68 + fm];
            pp[0]  = (_Float16)__expf(sa[0][r] - mn);
            pp[16] = (_Float16)__expf(sa[1][r] - mn);
            pp[32] = (_Float16)__expf(sa[2][r] - mn);
            pp[48] = (_Float16)__expf(sa[3][r] - mn);
            lacc[r] *= alpha;
            O[0][r] *= alpha; O[1][r] *= alpha; O[2][r] *= alpha; O[3][r] *= alpha;
        }
        // wave-private LDS: lgkmcnt ordering suffices, no barrier

        // ---- O += P V, l += P 1 : 10 MFMAs ----
        #pragma unroll
        for (int ch = 0; ch < 2; ++ch) {
            const half8 pa = *reinterpret_cast<const half8*>(&Ps[fm * 68 + ch * 32 + fk]);
            lacc = __builtin_amdgcn_mfma_f32_16x16x32_f16(pa, ones, lacc, 0, 0, 0);
            #pragma unroll
            for (int ht = 0; ht < 4; ++ht) {
                const half8 vb = *reinterpret_cast<const half8*>(
                    &vpb[(size_t)(jj * 4 + ht) * 1024 + ch * 512 + loff]);
                O[ht] = __builtin_amdgcn_mfma_f32_16x16x32_f16(pa, vb, O[ht], 0, 0, 0);
            }
        }
    }

    // ---- epilogue: write segment partial (unnormalized O, m, l) ----
    #pragma unroll
    for (int r = 0; r < 4; ++r) {
        const int grow = (b * 128 + it) * 16 + fr + r;
        if (s == 0) {
            #pragma unroll
            for (int ht = 0; ht < 4; ++ht)
                out[(size_t)grow * HH + ht * 16 + fm] = O[ht][r];
        } else {
            #pragma unroll
            for (int ht = 0; ht < 4; ++ht)
                Op[((size_t)(s - 1) * MM + grow) * HH + ht * 16 + fm] = (_Float16)O[ht][r];
        }
        if (fm == 0) {
            ml[((size_t)s * MM + grow) * 2 + 0] = m_r[r];
            ml[((size_t)s * MM + grow) * 2 + 1] = lacc[r];
        }
    }
}

// ---------------------------------------------------------------------------
// Kernel 3: flash-decode combine of the 3 segment partials.
// ---------------------------------------------------------------------------
__global__ __launch_bounds__(256)
void combine(float* __restrict__ out, const _Float16* __restrict__ Op,
             const float* __restrict__ ml)
{
    const int tid  = threadIdx.x;
    const int grow = blockIdx.x * 64 + (tid >> 2);
    const int c0   = (tid & 3) * 16;

    const float m0 = ml[(size_t)grow * 2 + 0];
    const float l0 = ml[(size_t)grow * 2 + 1];
    const float m1 = ml[((size_t)MM + grow) * 2 + 0];
    const float l1 = ml[((size_t)MM + grow) * 2 + 1];
    const float m2 = ml[((size_t)2 * MM + grow) * 2 + 0];
    const float l2 = ml[((size_t)2 * MM + grow) * 2 + 1];

    const float M  = fmaxf(m0, fmaxf(m1, m2));
    const float w0 = __expf(m0 - M);
    const float w1 = __expf(m1 - M);
    const float w2 = __expf(m2 - M);
    const float inv = 1.0f / (w0 * l0 + w1 * l1 + w2 * l2);

    #pragma unroll
    for (int i = 0; i < 16; i += 4) {
        float4 o0 = *reinterpret_cast<float4*>(&out[(size_t)grow * HH + c0 + i]);
        const half4 h1 = *reinterpret_cast<const half4*>(&Op[(size_t)grow * HH + c0 + i]);
        const half4 h2 = *reinterpret_cast<const half4*>(&Op[(size_t)MM * HH + (size_t)grow * HH + c0 + i]);
        o0.x = (w0 * o0.x + w1 * (float)h1[0] + w2 * (float)h2[0]) * inv;
        o0.y = (w0 * o0.y + w1 * (float)h1[1] + w2 * (float)h2[1]) * inv;
        o0.z = (w0 * o0.z + w1 * (float)h1[2] + w2 * (float)h2[2]) * inv;
        o0.w = (w0 * o0.w + w1 * (float)h1[3] + w2 * (float)h2[3]) * inv;
        *reinterpret_cast<float4*>(&out[(size_t)grow * HH + c0 + i]) = o0;
    }
}

// ---------------------------------------------------------------------------
extern "C" void kernel_launch(void* const* d_in, const int* in_sizes, int n_in,
                              void* d_out, int out_size, void* d_ws, size_t ws_size,
                              hipStream_t stream)
{
    (void)in_sizes; (void)n_in; (void)out_size; (void)ws_size;

    const float* x  = (const float*)d_in[0];
    const float* Wk = (const float*)d_in[1];
    const float* Wq = (const float*)d_in[2];
    const float* Wv = (const float*)d_in[3];
    float* out = (float*)d_out;

    _Float16* base = (_Float16*)d_ws;
    _Float16* q16 = base;                                  // MM*HH halves
    _Float16* Kp  = base + (size_t)MM * HH;                // MM*HH
    _Float16* Vp  = base + (size_t)2 * MM * HH;            // MM*HH
    _Float16* Wp  = base + (size_t)3 * MM * HH;            // 192*1024
    _Float16* Op  = Wp + 192 * 1024;                       // 2*MM*HH
    float*    ml  = (float*)(Op + (size_t)2 * MM * HH);    // 3*MM*2 floats

    w_pack<<<dim3(96), dim3(256), 0, stream>>>(Wk, Wq, Wv, Wp);
    qkv7<<<dim3(2048), dim3(64), 0, stream>>>(x, Wp, q16, Kp, Vp);
    attn7<<<dim3(3072), dim3(64), 0, stream>>>(q16, Kp, Vp, out, Op, ml);
    combine<<<dim3(256), dim3(256), 0, stream>>>(out, Op, ml);
}